// Round 16
// baseline (361.948 us; speedup 1.0000x reference)
//
#include <hip/hip_runtime.h>
#include <hip/hip_bf16.h>

#define NF 64        // node/edge feature dim
#define N_OUT 128    // output dim
#define CAT 192      // concat dim = 3*64
#define CAPL 6       // log2 bin capacity
#define CAP 64       // slots per node (P(overflow) ~ 1e-10 for Poisson(20))

typedef __attribute__((ext_vector_type(4))) float f32x4;
typedef __attribute__((ext_vector_type(8))) short bf16x8;

__device__ inline unsigned short f2bf(float x) {   // round-to-nearest-even bf16
  unsigned u = __float_as_uint(x);
  unsigned r = (u + 0x7fff + ((u >> 16) & 1)) >> 16;
  return (unsigned short)r;
}

__device__ inline ushort4 pack4(f32x4 v) {
  ushort4 r;
  r.x = f2bf(v.x); r.y = f2bf(v.y); r.z = f2bf(v.z); r.w = f2bf(v.w);
  return r;
}

__device__ inline f32x4 unpack4(ushort4 b) {
  f32x4 v;
  v.x = __uint_as_float((unsigned)b.x << 16);
  v.y = __uint_as_float((unsigned)b.y << 16);
  v.z = __uint_as_float((unsigned)b.z << 16);
  v.w = __uint_as_float((unsigned)b.w << 16);
  return v;
}

__device__ inline f32x4 sx4(f32x4 v, int m) {
  f32x4 r;
  r.x = __shfl_xor(v.x, m, 64);
  r.y = __shfl_xor(v.y, m, 64);
  r.z = __shfl_xor(v.z, m, 64);
  r.w = __shfl_xor(v.w, m, 64);
  return r;
}

// ---------------- bin fill: one atomic per edge ----------------
__global__ __launch_bounds__(1024) void fill_kernel(const int* __restrict__ src,
                                                    const int* __restrict__ dst,
                                                    int* __restrict__ cnt,
                                                    long long* __restrict__ bins,
                                                    int n_edges) {
  int i = blockIdx.x * blockDim.x + threadIdx.x;
  if (i >= n_edges) return;
  int d = __builtin_nontemporal_load(&dst[i]);
  int s = __builtin_nontemporal_load(&src[i]);
  int p = atomicAdd(&cnt[d], 1) & (CAP - 1);   // clamp: memory-safe
  long long pk = (long long)(((unsigned long long)(unsigned)s << 32) | (unsigned)i);
  bins[((size_t)d << CAPL) + p] = pk;   // cached: merges in L2/L3, re-read by h1/h2
}

// ---------------- hop 1: gather f32 edge rows from bins; norm inline ----------------
__global__ __launch_bounds__(256) void h1_kernel(const float* __restrict__ edge_feat,
                                                 const float* __restrict__ node_feat,
                                                 const int2* __restrict__ bins,
                                                 const int* __restrict__ cnt,
                                                 unsigned short* __restrict__ h1r,
                                                 unsigned short* __restrict__ h1n,
                                                 unsigned short* __restrict__ nfb,
                                                 int n_nodes) {
  int n = blockIdx.x * 4 + (threadIdx.x >> 6);
  if (n >= n_nodes) return;
  int l = threadIdx.x & 63;
  int l15 = l & 15, l4 = l >> 4;
  int c = cnt[n];
  if (c > CAP) c = CAP;
  int kb = n << CAPL;
  int ke = kb + c;
  f32x4 acc[4];
  acc[0] = f32x4{0.f,0.f,0.f,0.f}; acc[1] = f32x4{0.f,0.f,0.f,0.f};
  acc[2] = f32x4{0.f,0.f,0.f,0.f}; acc[3] = f32x4{0.f,0.f,0.f,0.f};
  int k = kb;
  for (; k + 16 <= ke; k += 16) {
    int e0 = bins[k + l4].x;
    int e1 = bins[k + 4 + l4].x;
    int e2 = bins[k + 8 + l4].x;
    int e3 = bins[k + 12 + l4].x;
    acc[0] += __builtin_nontemporal_load((const f32x4*)&edge_feat[(size_t)e0 * NF + l15 * 4]);
    acc[1] += __builtin_nontemporal_load((const f32x4*)&edge_feat[(size_t)e1 * NF + l15 * 4]);
    acc[2] += __builtin_nontemporal_load((const f32x4*)&edge_feat[(size_t)e2 * NF + l15 * 4]);
    acc[3] += __builtin_nontemporal_load((const f32x4*)&edge_feat[(size_t)e3 * NF + l15 * 4]);
  }
  // rotating-accumulator tail: up to 3 quad-iters + remainder, ILP preserved
  int rot = 0;
  for (; k + 4 <= ke; k += 4, ++rot) {
    int e = bins[k + l4].x;
    acc[rot & 3] += __builtin_nontemporal_load((const f32x4*)&edge_feat[(size_t)e * NF + l15 * 4]);
  }
  int rem = ke - k;   // 0..3
  if (l4 < rem) {
    int e = bins[k + l4].x;
    acc[3] += __builtin_nontemporal_load((const f32x4*)&edge_feat[(size_t)e * NF + l15 * 4]);
  }
  f32x4 t = (acc[0] + acc[1]) + (acc[2] + acc[3]);
  t += sx4(t, 16);
  t += sx4(t, 32);
  if (l4 == 0) {
    *(ushort4*)&h1r[(size_t)n * NF + l15 * 4] = pack4(t);
    float nm = rsqrtf(fmaxf((float)c, 1.0f));
    f32x4 tn = t; tn.x *= nm; tn.y *= nm; tn.z *= nm; tn.w *= nm;
    *(ushort4*)&h1n[(size_t)n * NF + l15 * 4] = pack4(tn);
  } else if (l4 == 1) {
    f32x4 v = *(const f32x4*)&node_feat[(size_t)n * NF + l15 * 4];
    *(ushort4*)&nfb[(size_t)n * NF + l15 * 4] = pack4(v);
  }
}

// ---------------- hop 2: gather bf16 h1r rows via bin src ids; norm inline ----------
__global__ __launch_bounds__(256) void h2_kernel(const unsigned short* __restrict__ h1r,
                                                 const int2* __restrict__ bins,
                                                 const int* __restrict__ cnt,
                                                 unsigned short* __restrict__ h2n,
                                                 int n_nodes) {
  int n = blockIdx.x * 4 + (threadIdx.x >> 6);
  if (n >= n_nodes) return;
  int l = threadIdx.x & 63;
  int l15 = l & 15, l4 = l >> 4;
  int c = cnt[n];
  if (c > CAP) c = CAP;
  int kb = n << CAPL;
  int ke = kb + c;
  f32x4 acc[4];
  acc[0] = f32x4{0.f,0.f,0.f,0.f}; acc[1] = f32x4{0.f,0.f,0.f,0.f};
  acc[2] = f32x4{0.f,0.f,0.f,0.f}; acc[3] = f32x4{0.f,0.f,0.f,0.f};
  int k = kb;
  for (; k + 16 <= ke; k += 16) {
    int s0 = bins[k + l4].y;
    int s1 = bins[k + 4 + l4].y;
    int s2 = bins[k + 8 + l4].y;
    int s3 = bins[k + 12 + l4].y;
    acc[0] += unpack4(*(const ushort4*)&h1r[(size_t)s0 * NF + l15 * 4]);
    acc[1] += unpack4(*(const ushort4*)&h1r[(size_t)s1 * NF + l15 * 4]);
    acc[2] += unpack4(*(const ushort4*)&h1r[(size_t)s2 * NF + l15 * 4]);
    acc[3] += unpack4(*(const ushort4*)&h1r[(size_t)s3 * NF + l15 * 4]);
  }
  int rot = 0;
  for (; k + 4 <= ke; k += 4, ++rot) {
    int s = bins[k + l4].y;
    acc[rot & 3] += unpack4(*(const ushort4*)&h1r[(size_t)s * NF + l15 * 4]);
  }
  int rem = ke - k;
  if (l4 < rem) {
    int s = bins[k + l4].y;
    acc[3] += unpack4(*(const ushort4*)&h1r[(size_t)s * NF + l15 * 4]);
  }
  f32x4 t = (acc[0] + acc[1]) + (acc[2] + acc[3]);
  t += sx4(t, 16);
  t += sx4(t, 32);
  if (l4 == 0) {
    float nm = rsqrtf(fmaxf((float)c, 1.0f));
    t.x *= nm; t.y *= nm; t.z *= nm; t.w *= nm;
    *(ushort4*)&h2n[(size_t)n * NF + l15 * 4] = pack4(t);
  }
}

// ---------------- GEMM via bf16 MFMA: 512 thr, 64-node tile, rst + bf16 shadow ----
__global__ __launch_bounds__(512) void gemm_kernel(const unsigned short* __restrict__ nfb,
                                                   const unsigned short* __restrict__ h1n,
                                                   const unsigned short* __restrict__ h2n,
                                                   const float* __restrict__ W,
                                                   const float* __restrict__ bias,
                                                   float* __restrict__ rst,
                                                   unsigned short* __restrict__ rstb,
                                                   int n_nodes) {
  __shared__ short F[64 * 200];
  __shared__ float R[64][132];
  int tid = threadIdx.x;
  int l = tid & 63, w = tid >> 6;
  int w2 = w & 3, wh = w >> 2;
  int l15 = l & 15, l4 = l >> 4;

  bf16x8 Bf[6][2];
  #pragma unroll
  for (int c = 0; c < 2; ++c) {
    int col = w2 * 32 + c * 16 + l15;
    const float* wp = &W[(size_t)col * CAT];
    #pragma unroll
    for (int ks = 0; ks < 6; ++ks) {
      int k0 = ks * 32 + l4 * 8;
      bf16x8 b;
      #pragma unroll
      for (int j = 0; j < 8; ++j) b[j] = (short)f2bf(wp[k0 + j]);
      Bf[ks][c] = b;
    }
  }
  float bias0 = bias[w2 * 32 + l15];
  float bias1 = bias[w2 * 32 + 16 + l15];

  int tiles = (n_nodes + 63) / 64;
  for (int tile = blockIdx.x; tile < tiles; tile += gridDim.x) {
    int nbase = tile * 64;
    __syncthreads();
    for (int idx = tid; idx < 1536; idx += 512) {
      int m = idx / 24, q = idx - m * 24;
      int n = nbase + m;
      bf16x8 pk = bf16x8{0,0,0,0,0,0,0,0};
      if (n < n_nodes) {
        const unsigned short* base = (q < 8) ? nfb : (q < 16) ? h1n : h2n;
        pk = *(const bf16x8*)&base[(size_t)n * NF + (q & 7) * 8];
      }
      *(bf16x8*)&F[m * 200 + q * 8] = pk;
    }
    __syncthreads();
    f32x4 acc00 = {0.f,0.f,0.f,0.f}, acc01 = {0.f,0.f,0.f,0.f};
    f32x4 acc10 = {0.f,0.f,0.f,0.f}, acc11 = {0.f,0.f,0.f,0.f};
    #pragma unroll
    for (int ks = 0; ks < 6; ++ks) {
      bf16x8 a0 = *(const bf16x8*)&F[(wh * 32 + l15) * 200 + ks * 32 + l4 * 8];
      bf16x8 a1 = *(const bf16x8*)&F[(wh * 32 + 16 + l15) * 200 + ks * 32 + l4 * 8];
      acc00 = __builtin_amdgcn_mfma_f32_16x16x32_bf16(a0, Bf[ks][0], acc00, 0, 0, 0);
      acc01 = __builtin_amdgcn_mfma_f32_16x16x32_bf16(a0, Bf[ks][1], acc01, 0, 0, 0);
      acc10 = __builtin_amdgcn_mfma_f32_16x16x32_bf16(a1, Bf[ks][0], acc10, 0, 0, 0);
      acc11 = __builtin_amdgcn_mfma_f32_16x16x32_bf16(a1, Bf[ks][1], acc11, 0, 0, 0);
    }
    #pragma unroll
    for (int rt = 0; rt < 2; ++rt) {
      f32x4 ac0 = rt ? acc10 : acc00;
      f32x4 ac1 = rt ? acc11 : acc01;
      #pragma unroll
      for (int r = 0; r < 4; ++r) {
        int row = wh * 32 + rt * 16 + l4 * 4 + r;
        R[row][w2 * 32 + l15] = ac0[r] + bias0;
        R[row][w2 * 32 + 16 + l15] = ac1[r] + bias1;
      }
    }
    __syncthreads();
    for (int idx = tid; idx < 64 * 32; idx += 512) {
      int m = idx >> 5, c = idx & 31;
      int n = nbase + m;
      if (n < n_nodes) {
        f32x4 v = *(const f32x4*)&R[m][c * 4];
        __builtin_nontemporal_store(v, (f32x4*)&rst[(size_t)n * N_OUT + c * 4]);
      }
    }
    for (int idx = tid; idx < 64 * 16; idx += 512) {
      int m = idx >> 4, q = idx & 15;
      int n = nbase + m;
      if (n < n_nodes) {
        const float* rp = &R[m][q * 8];
        bf16x8 pk;
        #pragma unroll
        for (int j = 0; j < 8; ++j) pk[j] = (short)f2bf(rp[j]);
        *(bf16x8*)&rstb[(size_t)n * N_OUT + q * 8] = pk;
      }
    }
  }
}

// ---------------- est: 32B/lane — ushort8 read -> two f32x4 NT writes ----------
__global__ __launch_bounds__(256) void est_bf16_kernel(const unsigned short* __restrict__ rstb,
                                                       const int* __restrict__ src,
                                                       float* __restrict__ est, int n_edges) {
  f32x4* e4 = (f32x4*)est;
  int total = n_edges * 16;   // 16 x 32B chunks per edge
  int i = blockIdx.x * blockDim.x + threadIdx.x;
  int stride = gridDim.x * blockDim.x;
  for (; i < total; i += stride) {
    int e = i >> 4, c = i & 15;
    const ushort4* rp = (const ushort4*)&rstb[(size_t)src[e] * N_OUT + c * 8];
    ushort4 b0 = rp[0];
    ushort4 b1 = rp[1];
    __builtin_nontemporal_store(unpack4(b0), &e4[i * 2]);
    __builtin_nontemporal_store(unpack4(b1), &e4[i * 2 + 1]);
  }
}

extern "C" void kernel_launch(void* const* d_in, const int* in_sizes, int n_in,
                              void* d_out, int out_size, void* d_ws, size_t ws_size,
                              hipStream_t stream) {
  const float* node_feat = (const float*)d_in[0];
  const float* edge_feat = (const float*)d_in[1];
  const float* W = (const float*)d_in[2];
  const float* bias = (const float*)d_in[3];
  const int* src = (const int*)d_in[4];
  const int* dst = (const int*)d_in[5];
  int n_nodes = in_sizes[0] / NF;
  int n_edges = in_sizes[4];

  size_t off = 0;
  auto take = [&](size_t bytes) -> void* {
    void* p = (char*)d_ws + off;
    off += (bytes + 255) & ~(size_t)255;
    return p;
  };
  int* cnt = (int*)take((size_t)n_nodes * 4);
  long long* bins = (long long*)take((size_t)n_nodes * CAP * 8);
  unsigned short* h1r = (unsigned short*)take((size_t)n_nodes * NF * 2);
  unsigned short* h1n = (unsigned short*)take((size_t)n_nodes * NF * 2);
  unsigned short* h2n = (unsigned short*)take((size_t)n_nodes * NF * 2);
  unsigned short* nfb = (unsigned short*)take((size_t)n_nodes * NF * 2);
  unsigned short* rstb = (unsigned short*)take((size_t)n_nodes * N_OUT * 2);

  float* rst = (float*)d_out;
  float* est = rst + (size_t)n_nodes * N_OUT;

  (void)hipMemsetAsync(cnt, 0, (size_t)n_nodes * 4, stream);

  fill_kernel<<<(n_edges + 1023) / 1024, 1024, 0, stream>>>(src, dst, cnt, bins, n_edges);
  int nb = (n_nodes + 3) / 4;
  h1_kernel<<<nb, 256, 0, stream>>>(edge_feat, node_feat, (const int2*)bins, cnt,
                                    h1r, h1n, nfb, n_nodes);
  h2_kernel<<<nb, 256, 0, stream>>>(h1r, (const int2*)bins, cnt, h2n, n_nodes);
  gemm_kernel<<<512, 512, 0, stream>>>(nfb, h1n, h2n, W, bias, rst, rstb, n_nodes);
  est_bf16_kernel<<<8192, 256, 0, stream>>>(rstb, src, est, n_edges);
}

// Round 17
// 320.976 us; speedup vs baseline: 1.1276x; 1.1276x over previous
//
#include <hip/hip_runtime.h>
#include <hip/hip_bf16.h>

#define NF 64        // node/edge feature dim
#define N_OUT 128    // output dim
#define CAT 192      // concat dim = 3*64
#define CAPL 6       // log2 bin capacity
#define CAP 64       // slots per node (P(overflow) ~ 1e-10 for Poisson(20))

typedef __attribute__((ext_vector_type(4))) float f32x4;
typedef __attribute__((ext_vector_type(8))) short bf16x8;

__device__ inline unsigned short f2bf(float x) {   // round-to-nearest-even bf16
  unsigned u = __float_as_uint(x);
  unsigned r = (u + 0x7fff + ((u >> 16) & 1)) >> 16;
  return (unsigned short)r;
}

__device__ inline ushort4 pack4(f32x4 v) {
  ushort4 r;
  r.x = f2bf(v.x); r.y = f2bf(v.y); r.z = f2bf(v.z); r.w = f2bf(v.w);
  return r;
}

__device__ inline f32x4 unpack4(ushort4 b) {
  f32x4 v;
  v.x = __uint_as_float((unsigned)b.x << 16);
  v.y = __uint_as_float((unsigned)b.y << 16);
  v.z = __uint_as_float((unsigned)b.z << 16);
  v.w = __uint_as_float((unsigned)b.w << 16);
  return v;
}

__device__ inline f32x4 sx4(f32x4 v, int m) {
  f32x4 r;
  r.x = __shfl_xor(v.x, m, 64);
  r.y = __shfl_xor(v.y, m, 64);
  r.z = __shfl_xor(v.z, m, 64);
  r.w = __shfl_xor(v.w, m, 64);
  return r;
}

// ---------------- bin fill: one atomic per edge, no deg/scan passes ----------------
// bins[d*CAP + p] = (src << 32) | edge_id ; cnt[d] = in-degree afterwards.
// Store is CACHED (not NT): bins fits in L3, partial lines merge there and
// h1/h2 re-read from cache.
__global__ __launch_bounds__(256) void fill_kernel(const int* __restrict__ src,
                                                   const int* __restrict__ dst,
                                                   int* __restrict__ cnt,
                                                   long long* __restrict__ bins,
                                                   int n_edges) {
  int i = blockIdx.x * blockDim.x + threadIdx.x;
  if (i >= n_edges) return;
  int d = __builtin_nontemporal_load(&dst[i]);
  int s = __builtin_nontemporal_load(&src[i]);
  int p = atomicAdd(&cnt[d], 1) & (CAP - 1);   // clamp: memory-safe
  long long pk = (long long)(((unsigned long long)(unsigned)s << 32) | (unsigned)i);
  bins[((size_t)d << CAPL) + p] = pk;
}

// ---------------- hop 1: gather f32 edge rows from bins; norm inline ----------------
__global__ __launch_bounds__(256) void h1_kernel(const float* __restrict__ edge_feat,
                                                 const float* __restrict__ node_feat,
                                                 const int2* __restrict__ bins,
                                                 const int* __restrict__ cnt,
                                                 unsigned short* __restrict__ h1r,
                                                 unsigned short* __restrict__ h1n,
                                                 unsigned short* __restrict__ nfb,
                                                 int n_nodes) {
  int n = blockIdx.x * 4 + (threadIdx.x >> 6);
  if (n >= n_nodes) return;
  int l = threadIdx.x & 63;
  int l15 = l & 15, l4 = l >> 4;
  int c = cnt[n];
  if (c > CAP) c = CAP;
  int kb = n << CAPL;
  int ke = kb + c;
  f32x4 acc0 = {0.f,0.f,0.f,0.f}, acc1 = {0.f,0.f,0.f,0.f};
  f32x4 acc2 = {0.f,0.f,0.f,0.f}, acc3 = {0.f,0.f,0.f,0.f};
  int k = kb;
  for (; k + 16 <= ke; k += 16) {
    int e0 = bins[k + l4].x;
    int e1 = bins[k + 4 + l4].x;
    int e2 = bins[k + 8 + l4].x;
    int e3 = bins[k + 12 + l4].x;
    acc0 += __builtin_nontemporal_load((const f32x4*)&edge_feat[(size_t)e0 * NF + l15 * 4]);
    acc1 += __builtin_nontemporal_load((const f32x4*)&edge_feat[(size_t)e1 * NF + l15 * 4]);
    acc2 += __builtin_nontemporal_load((const f32x4*)&edge_feat[(size_t)e2 * NF + l15 * 4]);
    acc3 += __builtin_nontemporal_load((const f32x4*)&edge_feat[(size_t)e3 * NF + l15 * 4]);
  }
  if (k + 8 <= ke) {
    int e0 = bins[k + l4].x;
    int e1 = bins[k + 4 + l4].x;
    acc0 += __builtin_nontemporal_load((const f32x4*)&edge_feat[(size_t)e0 * NF + l15 * 4]);
    acc1 += __builtin_nontemporal_load((const f32x4*)&edge_feat[(size_t)e1 * NF + l15 * 4]);
    k += 8;
  }
  if (k + 4 <= ke) {
    int e = bins[k + l4].x;
    acc2 += __builtin_nontemporal_load((const f32x4*)&edge_feat[(size_t)e * NF + l15 * 4]);
    k += 4;
  }
  int rem = ke - k;   // 0..3
  if (l4 < rem) {
    int e = bins[k + l4].x;
    acc3 += __builtin_nontemporal_load((const f32x4*)&edge_feat[(size_t)e * NF + l15 * 4]);
  }
  f32x4 t = (acc0 + acc1) + (acc2 + acc3);
  t += sx4(t, 16);
  t += sx4(t, 32);
  if (l4 == 0) {
    *(ushort4*)&h1r[(size_t)n * NF + l15 * 4] = pack4(t);
    float nm = rsqrtf(fmaxf((float)c, 1.0f));
    f32x4 tn = t; tn.x *= nm; tn.y *= nm; tn.z *= nm; tn.w *= nm;
    *(ushort4*)&h1n[(size_t)n * NF + l15 * 4] = pack4(tn);
  } else if (l4 == 1) {
    f32x4 v = *(const f32x4*)&node_feat[(size_t)n * NF + l15 * 4];
    *(ushort4*)&nfb[(size_t)n * NF + l15 * 4] = pack4(v);
  }
}

// ---------------- hop 2: gather bf16 h1r rows via bin src ids; norm inline ----------
__global__ __launch_bounds__(256) void h2_kernel(const unsigned short* __restrict__ h1r,
                                                 const int2* __restrict__ bins,
                                                 const int* __restrict__ cnt,
                                                 unsigned short* __restrict__ h2n,
                                                 int n_nodes) {
  int n = blockIdx.x * 4 + (threadIdx.x >> 6);
  if (n >= n_nodes) return;
  int l = threadIdx.x & 63;
  int l15 = l & 15, l4 = l >> 4;
  int c = cnt[n];
  if (c > CAP) c = CAP;
  int kb = n << CAPL;
  int ke = kb + c;
  f32x4 acc0 = {0.f,0.f,0.f,0.f}, acc1 = {0.f,0.f,0.f,0.f};
  f32x4 acc2 = {0.f,0.f,0.f,0.f}, acc3 = {0.f,0.f,0.f,0.f};
  int k = kb;
  for (; k + 16 <= ke; k += 16) {
    int s0 = bins[k + l4].y;
    int s1 = bins[k + 4 + l4].y;
    int s2 = bins[k + 8 + l4].y;
    int s3 = bins[k + 12 + l4].y;
    acc0 += unpack4(*(const ushort4*)&h1r[(size_t)s0 * NF + l15 * 4]);
    acc1 += unpack4(*(const ushort4*)&h1r[(size_t)s1 * NF + l15 * 4]);
    acc2 += unpack4(*(const ushort4*)&h1r[(size_t)s2 * NF + l15 * 4]);
    acc3 += unpack4(*(const ushort4*)&h1r[(size_t)s3 * NF + l15 * 4]);
  }
  if (k + 8 <= ke) {
    int s0 = bins[k + l4].y;
    int s1 = bins[k + 4 + l4].y;
    acc0 += unpack4(*(const ushort4*)&h1r[(size_t)s0 * NF + l15 * 4]);
    acc1 += unpack4(*(const ushort4*)&h1r[(size_t)s1 * NF + l15 * 4]);
    k += 8;
  }
  if (k + 4 <= ke) {
    int s = bins[k + l4].y;
    acc2 += unpack4(*(const ushort4*)&h1r[(size_t)s * NF + l15 * 4]);
    k += 4;
  }
  int rem = ke - k;
  if (l4 < rem) {
    int s = bins[k + l4].y;
    acc3 += unpack4(*(const ushort4*)&h1r[(size_t)s * NF + l15 * 4]);
  }
  f32x4 t = (acc0 + acc1) + (acc2 + acc3);
  t += sx4(t, 16);
  t += sx4(t, 32);
  if (l4 == 0) {
    float nm = rsqrtf(fmaxf((float)c, 1.0f));
    t.x *= nm; t.y *= nm; t.z *= nm; t.w *= nm;
    *(ushort4*)&h2n[(size_t)n * NF + l15 * 4] = pack4(t);
  }
}

// ---------------- GEMM via bf16 MFMA: 512 thr, 64-node tile, rst + bf16 shadow ----
__global__ __launch_bounds__(512) void gemm_kernel(const unsigned short* __restrict__ nfb,
                                                   const unsigned short* __restrict__ h1n,
                                                   const unsigned short* __restrict__ h2n,
                                                   const float* __restrict__ W,
                                                   const float* __restrict__ bias,
                                                   float* __restrict__ rst,
                                                   unsigned short* __restrict__ rstb,
                                                   int n_nodes) {
  __shared__ short F[64 * 200];
  __shared__ float R[64][132];
  int tid = threadIdx.x;
  int l = tid & 63, w = tid >> 6;
  int w2 = w & 3, wh = w >> 2;
  int l15 = l & 15, l4 = l >> 4;

  bf16x8 Bf[6][2];
  #pragma unroll
  for (int c = 0; c < 2; ++c) {
    int col = w2 * 32 + c * 16 + l15;
    const float* wp = &W[(size_t)col * CAT];
    #pragma unroll
    for (int ks = 0; ks < 6; ++ks) {
      int k0 = ks * 32 + l4 * 8;
      bf16x8 b;
      #pragma unroll
      for (int j = 0; j < 8; ++j) b[j] = (short)f2bf(wp[k0 + j]);
      Bf[ks][c] = b;
    }
  }
  float bias0 = bias[w2 * 32 + l15];
  float bias1 = bias[w2 * 32 + 16 + l15];

  int tiles = (n_nodes + 63) / 64;
  for (int tile = blockIdx.x; tile < tiles; tile += gridDim.x) {
    int nbase = tile * 64;
    __syncthreads();
    for (int idx = tid; idx < 1536; idx += 512) {
      int m = idx / 24, q = idx - m * 24;
      int n = nbase + m;
      bf16x8 pk = bf16x8{0,0,0,0,0,0,0,0};
      if (n < n_nodes) {
        const unsigned short* base = (q < 8) ? nfb : (q < 16) ? h1n : h2n;
        pk = *(const bf16x8*)&base[(size_t)n * NF + (q & 7) * 8];
      }
      *(bf16x8*)&F[m * 200 + q * 8] = pk;
    }
    __syncthreads();
    f32x4 acc00 = {0.f,0.f,0.f,0.f}, acc01 = {0.f,0.f,0.f,0.f};
    f32x4 acc10 = {0.f,0.f,0.f,0.f}, acc11 = {0.f,0.f,0.f,0.f};
    #pragma unroll
    for (int ks = 0; ks < 6; ++ks) {
      bf16x8 a0 = *(const bf16x8*)&F[(wh * 32 + l15) * 200 + ks * 32 + l4 * 8];
      bf16x8 a1 = *(const bf16x8*)&F[(wh * 32 + 16 + l15) * 200 + ks * 32 + l4 * 8];
      acc00 = __builtin_amdgcn_mfma_f32_16x16x32_bf16(a0, Bf[ks][0], acc00, 0, 0, 0);
      acc01 = __builtin_amdgcn_mfma_f32_16x16x32_bf16(a0, Bf[ks][1], acc01, 0, 0, 0);
      acc10 = __builtin_amdgcn_mfma_f32_16x16x32_bf16(a1, Bf[ks][0], acc10, 0, 0, 0);
      acc11 = __builtin_amdgcn_mfma_f32_16x16x32_bf16(a1, Bf[ks][1], acc11, 0, 0, 0);
    }
    #pragma unroll
    for (int rt = 0; rt < 2; ++rt) {
      f32x4 ac0 = rt ? acc10 : acc00;
      f32x4 ac1 = rt ? acc11 : acc01;
      #pragma unroll
      for (int r = 0; r < 4; ++r) {
        int row = wh * 32 + rt * 16 + l4 * 4 + r;
        R[row][w2 * 32 + l15] = ac0[r] + bias0;
        R[row][w2 * 32 + 16 + l15] = ac1[r] + bias1;
      }
    }
    __syncthreads();
    for (int idx = tid; idx < 64 * 32; idx += 512) {
      int m = idx >> 5, c = idx & 31;
      int n = nbase + m;
      if (n < n_nodes) {
        f32x4 v = *(const f32x4*)&R[m][c * 4];
        __builtin_nontemporal_store(v, (f32x4*)&rst[(size_t)n * N_OUT + c * 4]);
      }
    }
    for (int idx = tid; idx < 64 * 16; idx += 512) {
      int m = idx >> 4, q = idx & 15;
      int n = nbase + m;
      if (n < n_nodes) {
        const float* rp = &R[m][q * 8];
        bf16x8 pk;
        #pragma unroll
        for (int j = 0; j < 8; ++j) pk[j] = (short)f2bf(rp[j]);
        *(bf16x8*)&rstb[(size_t)n * N_OUT + q * 8] = pk;
      }
    }
  }
}

// ---------------- est from bf16 shadow: sequential NT write, 256B gathers ----------
__global__ __launch_bounds__(256) void est_bf16_kernel(const unsigned short* __restrict__ rstb,
                                                       const int* __restrict__ src,
                                                       float* __restrict__ est, int n_edges) {
  f32x4* e4 = (f32x4*)est;
  int total = n_edges * 32;
  int i = blockIdx.x * blockDim.x + threadIdx.x;
  int stride = gridDim.x * blockDim.x;
  for (; i < total; i += stride) {
    int e = i >> 5, c = i & 31;
    ushort4 b = *(const ushort4*)&rstb[(size_t)src[e] * N_OUT + c * 4];
    __builtin_nontemporal_store(unpack4(b), &e4[i]);
  }
}

extern "C" void kernel_launch(void* const* d_in, const int* in_sizes, int n_in,
                              void* d_out, int out_size, void* d_ws, size_t ws_size,
                              hipStream_t stream) {
  const float* node_feat = (const float*)d_in[0];
  const float* edge_feat = (const float*)d_in[1];
  const float* W = (const float*)d_in[2];
  const float* bias = (const float*)d_in[3];
  const int* src = (const int*)d_in[4];
  const int* dst = (const int*)d_in[5];
  int n_nodes = in_sizes[0] / NF;
  int n_edges = in_sizes[4];

  size_t off = 0;
  auto take = [&](size_t bytes) -> void* {
    void* p = (char*)d_ws + off;
    off += (bytes + 255) & ~(size_t)255;
    return p;
  };
  int* cnt = (int*)take((size_t)n_nodes * 4);
  long long* bins = (long long*)take((size_t)n_nodes * CAP * 8);
  unsigned short* h1r = (unsigned short*)take((size_t)n_nodes * NF * 2);
  unsigned short* h1n = (unsigned short*)take((size_t)n_nodes * NF * 2);
  unsigned short* h2n = (unsigned short*)take((size_t)n_nodes * NF * 2);
  unsigned short* nfb = (unsigned short*)take((size_t)n_nodes * NF * 2);
  unsigned short* rstb = (unsigned short*)take((size_t)n_nodes * N_OUT * 2);

  float* rst = (float*)d_out;
  float* est = rst + (size_t)n_nodes * N_OUT;

  (void)hipMemsetAsync(cnt, 0, (size_t)n_nodes * 4, stream);

  fill_kernel<<<(n_edges + 255) / 256, 256, 0, stream>>>(src, dst, cnt, bins, n_edges);
  int nb = (n_nodes + 3) / 4;
  h1_kernel<<<nb, 256, 0, stream>>>(edge_feat, node_feat, (const int2*)bins, cnt,
                                    h1r, h1n, nfb, n_nodes);
  h2_kernel<<<nb, 256, 0, stream>>>(h1r, (const int2*)bins, cnt, h2n, n_nodes);
  gemm_kernel<<<512, 512, 0, stream>>>(nfb, h1n, h2n, W, bias, rst, rstb, n_nodes);
  est_bf16_kernel<<<8192, 256, 0, stream>>>(rstb, src, est, n_edges);
}